// Round 8
// baseline (287.484 us; speedup 1.0000x reference)
//
#include <hip/hip_runtime.h>
#include <hip/hip_bf16.h>

#define TT 8192
#define DD 64
#define BB 2
#define NROWS (BB * TT)  // 16384

typedef __attribute__((ext_vector_type(8))) short bf16x8;
typedef __attribute__((ext_vector_type(4))) float f32x4;
typedef _Float16 f16x4 __attribute__((ext_vector_type(4)));
typedef __fp16 fp16x2 __attribute__((ext_vector_type(2)));

#define MFMAQK __builtin_amdgcn_mfma_f32_16x16x32_bf16
#define MFMAPV __builtin_amdgcn_mfma_f32_16x16x16f16

typedef __attribute__((address_space(1))) const unsigned int gu32;
typedef __attribute__((address_space(3))) unsigned int lu32;

__device__ inline void gld_lds16(const unsigned short* g, unsigned short* l) {
  __builtin_amdgcn_global_load_lds((gu32*)g, (lu32*)l, 16, 0, 0);
}

// ws: xb bf16[16384*64] (2MB) | xth f16[2*64*8192] (2MB) | m fp32[16384] | mm fp32[16384]

__device__ inline unsigned short f2bf(float f) {
  unsigned int u = __float_as_uint(f);
  u += 0x7FFF + ((u >> 16) & 1);
  return (unsigned short)(u >> 16);
}
__device__ inline float bf2f(unsigned short h) {
  return __uint_as_float(((unsigned int)h) << 16);
}
__device__ inline f16x4 pk4f16(float a, float b, float c, float d) {
  union { fp16x2 h2[2]; f16x4 h4; } u;
  u.h2[0] = __builtin_amdgcn_cvt_pkrtz(a, b);
  u.h2[1] = __builtin_amdgcn_cvt_pkrtz(c, d);
  return u.h4;
}

// ---------- ka: bf16 xb + f16 transposed xth + m ----------
__global__ __launch_bounds__(256) void ka_init(const float* __restrict__ x,
                                               unsigned short* __restrict__ xb,
                                               unsigned short* __restrict__ xth,
                                               float* __restrict__ m) {
  __shared__ __align__(16) unsigned short tile[64 * 72];
  int t = threadIdx.x;
  int r0 = blockIdx.x * 64;
  int rloc = t >> 2, part = t & 3;
  int r = r0 + rloc;
  const float4* px = (const float4*)(x + (size_t)r * DD + part * 16);
  unsigned short h[16], hf[16];
  float msum = 0.f;
#pragma unroll
  for (int g = 0; g < 4; ++g) {
    float4 v = px[g];
    float vv[4] = {v.x, v.y, v.z, v.w};
#pragma unroll
    for (int e = 0; e < 4; ++e) {
      unsigned short hb = f2bf(vv[e]);
      h[g * 4 + e] = hb;
      float f = bf2f(hb);
      msum += f * f;
      _Float16 hh = (_Float16)vv[e];
      hf[g * 4 + e] = *(unsigned short*)&hh;
    }
  }
  uint4* xbr = (uint4*)(xb + (size_t)r * DD + part * 16);
#pragma unroll
  for (int g = 0; g < 2; ++g) {
    uint4 v;
    v.x = (unsigned int)h[g * 8 + 0] | ((unsigned int)h[g * 8 + 1] << 16);
    v.y = (unsigned int)h[g * 8 + 2] | ((unsigned int)h[g * 8 + 3] << 16);
    v.z = (unsigned int)h[g * 8 + 4] | ((unsigned int)h[g * 8 + 5] << 16);
    v.w = (unsigned int)h[g * 8 + 6] | ((unsigned int)h[g * 8 + 7] << 16);
    xbr[g] = v;
  }
#pragma unroll
  for (int k = 0; k < 16; ++k) tile[(part * 16 + k) * 72 + rloc] = hf[k];
  msum += __shfl_xor(msum, 1, 64);
  msum += __shfl_xor(msum, 2, 64);
  if (part == 0) m[r] = msum;
  __syncthreads();
  int d = t >> 2, seg = t & 3;
  int b = r0 >> 13;
  int tcol = (r0 & (TT - 1)) + seg * 16;
  uint4 v0 = *(uint4*)(tile + d * 72 + seg * 16);
  uint4 v1 = *(uint4*)(tile + d * 72 + seg * 16 + 8);
  uint4* dst = (uint4*)(xth + ((size_t)b * DD + d) * TT + tcol);
  dst[0] = v0;
  dst[1] = v1;
}

// ---------- kb: mm_j = m_j + ln(sum_k exp(x_j.x_k - m_j)) ----------
// 512 thr / 8 waves; block = 32 j; wave w sweeps k in [w*1024,(w+1)*1024),
// B-frags direct from global (register dbuf, compiler-managed waits).
__global__ __launch_bounds__(512, 4) void kb_l(const unsigned short* __restrict__ xq,
                                               const float* __restrict__ m,
                                               float* __restrict__ mm) {
  __shared__ float lpart[8][32];
  int w = threadIdx.x >> 6, lane = threadIdx.x & 63;
  int c = lane & 15, q = lane >> 4;
  int lid = blockIdx.x;
  int b = (lid >> 2) & 1;
  int tile = (lid & 3) | ((lid >> 3) << 2);  // 0..255
  int j0g = b * TT + tile * 32;
  bf16x8 a0[2], a1[2];
  f32x4 mv[2];
#pragma unroll
  for (int u = 0; u < 2; ++u) {
    const unsigned short* pr = xq + (size_t)(j0g + u * 16 + c) * DD + q * 8;
    a0[u] = *(const bf16x8*)pr;
    a1[u] = *(const bf16x8*)(pr + 32);
    mv[u] = *(const f32x4*)(m + j0g + u * 16 + 4 * q);
  }
  const unsigned short* xqb = xq + (size_t)(b * TT) * DD;
  int k0 = w * 1024;
  bf16x8 B[2][4];
  auto fetchB = [&](int buf, int kb_) {
    const unsigned short* p0 = xqb + (size_t)(kb_ + c) * DD + q * 8;
    const unsigned short* p1 = xqb + (size_t)(kb_ + 16 + c) * DD + q * 8;
    B[buf][0] = *(const bf16x8*)(p0);
    B[buf][1] = *(const bf16x8*)(p0 + 32);
    B[buf][2] = *(const bf16x8*)(p1);
    B[buf][3] = *(const bf16x8*)(p1 + 32);
  };
  fetchB(0, k0);
  float ls[2][4] = {{0.f, 0.f, 0.f, 0.f}, {0.f, 0.f, 0.f, 0.f}};
#pragma unroll 2
  for (int it = 0; it < 32; ++it) {
    int cur = it & 1;
    if (it < 31) fetchB(cur ^ 1, k0 + (it + 1) * 32);
#pragma unroll
    for (int u = 0; u < 2; ++u) {
      f32x4 z = {0.f, 0.f, 0.f, 0.f};
      f32x4 acc0 = MFMAQK(a0[u], B[cur][0], z, 0, 0, 0);
      acc0 = MFMAQK(a1[u], B[cur][1], acc0, 0, 0, 0);
      f32x4 acc1 = MFMAQK(a0[u], B[cur][2], z, 0, 0, 0);
      acc1 = MFMAQK(a1[u], B[cur][3], acc1, 0, 0, 0);
#pragma unroll
      for (int e = 0; e < 4; ++e)
        ls[u][e] += __expf(acc0[e] - mv[u][e]) + __expf(acc1[e] - mv[u][e]);
    }
  }
#pragma unroll
  for (int u = 0; u < 2; ++u)
#pragma unroll
    for (int e = 0; e < 4; ++e) {
      float v = ls[u][e];
      v += __shfl_xor(v, 1, 64);
      v += __shfl_xor(v, 2, 64);
      v += __shfl_xor(v, 4, 64);
      v += __shfl_xor(v, 8, 64);
      if (c == 0) lpart[w][u * 16 + 4 * q + e] = v;
    }
  __syncthreads();
  int t = threadIdx.x;
  if (t < 32) {
    float s = 0.f;
#pragma unroll
    for (int ww = 0; ww < 8; ++ww) s += lpart[ww][t];
    mm[j0g + t] = m[j0g + t] + __logf(s);
  }
}

// ---------- kc: out[b][d][i] = sum_j exp(x_j.x_i - mm_j) * x_j[d] ----------
// 512 thr / 8 waves; block = 32 i; wave w sweeps j in [w*1024,(w+1)*1024).
// A (QK) direct-global reg-dbuf; V (f16) per-wave DMA LDS dbuf; PV via
// 16x16x16 f16 MFMA (QK C-layout == PV A-layout: no transform).
__global__ __launch_bounds__(512, 4) void kc_out(const unsigned short* __restrict__ xq,
                                                 const unsigned short* __restrict__ xth,
                                                 const float* __restrict__ mm,
                                                 float* __restrict__ out) {
  __shared__ __align__(16) unsigned short smem[34816];  // 69632 B: V slabs 64KB | epi overlay
  int w = threadIdx.x >> 6, lane = threadIdx.x & 63;
  int c = lane & 15, q = lane >> 4;
  int lid = blockIdx.x;
  int b = (lid >> 2) & 1;
  int tile = (lid & 3) | ((lid >> 3) << 2);
  int i0 = tile * 32;
  bf16x8 bq0[2], bq1[2];
#pragma unroll
  for (int u = 0; u < 2; ++u) {
    const unsigned short* pr = xq + (size_t)(b * TT + i0 + u * 16 + c) * DD + q * 8;
    bq0[u] = *(const bf16x8*)pr;
    bq1[u] = *(const bf16x8*)(pr + 32);
  }
  f32x4 o[2][4];
#pragma unroll
  for (int u = 0; u < 2; ++u)
#pragma unroll
    for (int nt = 0; nt < 4; ++nt) o[u][nt] = (f32x4){0.f, 0.f, 0.f, 0.f};

  const unsigned short* xqb = xq + (size_t)(b * TT) * DD;
  const unsigned short* xtb = xth + (size_t)b * DD * TT;
  const float* mmb = mm + b * TT;
  int jq0 = w * 1024;
  unsigned short* vsb = smem + w * 4096;  // 2 bufs x 2048 shorts

  // V staging: inst t covers jh=t>>1, d-rows (t&1)*32+(lane>>1), chunk slot lane&1
  int vd = (lane >> 1);
  int vg = (lane & 1) ^ ((lane >> 1) & 1);  // stored chunk g at slot g^(d&1)
  auto stageV = [&](int buf, int j) {
#pragma unroll
    for (int t = 0; t < 4; ++t)
      gld_lds16(xtb + (size_t)((t & 1) * 32 + vd) * TT + j + (t >> 1) * 16 + 8 * vg,
                vsb + buf * 2048 + t * 512);
  };
  bf16x8 A[2][4];
  auto loadA = [&](int buf, int j) {
    const unsigned short* p0 = xqb + (size_t)(j + c) * DD + q * 8;
    const unsigned short* p1 = xqb + (size_t)(j + 16 + c) * DD + q * 8;
    A[buf][0] = *(const bf16x8*)(p0);
    A[buf][1] = *(const bf16x8*)(p0 + 32);
    A[buf][2] = *(const bf16x8*)(p1);
    A[buf][3] = *(const bf16x8*)(p1 + 32);
  };
  f32x4 mv0[2], mv1[2];
  stageV(0, jq0);
  loadA(0, jq0);
  mv0[0] = *(const f32x4*)(mmb + jq0 + 4 * q);
  mv1[0] = *(const f32x4*)(mmb + jq0 + 16 + 4 * q);

  // V read offset (shorts): row nt*16+c, chunk (q>>1)^(c&1), off 4*(q&1)
  int voff = c * 16 + 8 * ((q >> 1) ^ (c & 1)) + 4 * (q & 1);

#pragma unroll 2
  for (int it = 0; it < 32; ++it) {
    int cur = it & 1;
    int jt = jq0 + it * 32;
    if (it < 31) {
      stageV(cur ^ 1, jt + 32);
      loadA(cur ^ 1, jt + 32);
      mv0[cur ^ 1] = *(const f32x4*)(mmb + jt + 32 + 4 * q);
      mv1[cur ^ 1] = *(const f32x4*)(mmb + jt + 48 + 4 * q);
      __builtin_amdgcn_s_waitcnt(0xF7A);  // vmcnt(10): drain prev iter, keep prefetch in flight
    } else {
      __builtin_amdgcn_s_waitcnt(0xF70);  // vmcnt(0)
    }
    __builtin_amdgcn_sched_barrier(0);
    const unsigned short* vp = vsb + cur * 2048;
    f16x4 bv0[4], bv1[4];
#pragma unroll
    for (int nt = 0; nt < 4; ++nt) {
      bv0[nt] = *(const f16x4*)(vp + nt * 256 + voff);
      bv1[nt] = *(const f16x4*)(vp + 1024 + nt * 256 + voff);
    }
#pragma unroll
    for (int u = 0; u < 2; ++u) {
      f32x4 z = {0.f, 0.f, 0.f, 0.f};
      f32x4 s0 = MFMAQK(A[cur][0], bq0[u], z, 0, 0, 0);
      s0 = MFMAQK(A[cur][1], bq1[u], s0, 0, 0, 0);
      f32x4 s1 = MFMAQK(A[cur][2], bq0[u], z, 0, 0, 0);
      s1 = MFMAQK(A[cur][3], bq1[u], s1, 0, 0, 0);
      f16x4 p0 = pk4f16(__expf(s0[0] - mv0[cur][0]), __expf(s0[1] - mv0[cur][1]),
                        __expf(s0[2] - mv0[cur][2]), __expf(s0[3] - mv0[cur][3]));
      f16x4 p1 = pk4f16(__expf(s1[0] - mv1[cur][0]), __expf(s1[1] - mv1[cur][1]),
                        __expf(s1[2] - mv1[cur][2]), __expf(s1[3] - mv1[cur][3]));
#pragma unroll
      for (int nt = 0; nt < 4; ++nt) {
        o[u][nt] = MFMAPV(p0, bv0[nt], o[u][nt], 0, 0, 0);
        o[u][nt] = MFMAPV(p1, bv1[nt], o[u][nt], 0, 0, 0);
      }
    }
  }
  // cross-wave O reduce: per wave 64 d-rows x pitch 34 fp32 (8704 B)
  __syncthreads();
  float* ow = (float*)smem + w * 2176;
#pragma unroll
  for (int u = 0; u < 2; ++u)
#pragma unroll
    for (int nt = 0; nt < 4; ++nt)
      *(f32x4*)(ow + (nt * 16 + c) * 34 + u * 16 + 4 * q) = o[u][nt];
  __syncthreads();
  int t = threadIdx.x, d = t >> 3, i4 = (t & 7) * 4;
  const float* sbase = (const float*)smem;
  f32x4 s = {0.f, 0.f, 0.f, 0.f};
#pragma unroll
  for (int ww = 0; ww < 8; ++ww) s += *(const f32x4*)(sbase + ww * 2176 + d * 34 + i4);
  *(f32x4*)(out + ((size_t)(b * DD + d)) * TT + i0 + i4) = s;
}

extern "C" void kernel_launch(void* const* d_in, const int* in_sizes, int n_in,
                              void* d_out, int out_size, void* d_ws, size_t ws_size,
                              hipStream_t stream) {
  const float* x = (const float*)d_in[0];
  float* out = (float*)d_out;
  unsigned short* xb = (unsigned short*)d_ws;
  unsigned short* xth = xb + (size_t)NROWS * DD;
  float* m = (float*)(xth + (size_t)NROWS * DD);
  float* mmv = m + NROWS;

  ka_init<<<NROWS / 64, 256, 0, stream>>>(x, xb, xth, m);
  kb_l<<<512, 512, 0, stream>>>(xb, m, mmv);
  kc_out<<<512, 512, 0, stream>>>(xb, xth, mmv, out);
}

// Round 9
// 262.536 us; speedup vs baseline: 1.0950x; 1.0950x over previous
//
#include <hip/hip_runtime.h>
#include <hip/hip_bf16.h>

#define TT 8192
#define DD 64
#define BB 2
#define NROWS (BB * TT)  // 16384

typedef __attribute__((ext_vector_type(8))) short bf16x8;
typedef __attribute__((ext_vector_type(4))) float f32x4;
typedef _Float16 f16x4 __attribute__((ext_vector_type(4)));
typedef __fp16 fp16x2 __attribute__((ext_vector_type(2)));

#define MFMAQK __builtin_amdgcn_mfma_f32_16x16x32_bf16
#define MFMAPV __builtin_amdgcn_mfma_f32_16x16x16f16

typedef __attribute__((address_space(1))) const unsigned int gu32;
typedef __attribute__((address_space(3))) unsigned int lu32;

__device__ inline void gld_lds16(const unsigned short* g, unsigned short* l) {
  __builtin_amdgcn_global_load_lds((gu32*)g, (lu32*)l, 16, 0, 0);
}

// ws: xb bf16[16384*64] (2MB) | xth f16[2*64*8192] (2MB) | m fp32[16384] | mm fp32[16384]

__device__ inline unsigned short f2bf(float f) {
  unsigned int u = __float_as_uint(f);
  u += 0x7FFF + ((u >> 16) & 1);
  return (unsigned short)(u >> 16);
}
__device__ inline float bf2f(unsigned short h) {
  return __uint_as_float(((unsigned int)h) << 16);
}
__device__ inline f16x4 pk4f16(float a, float b, float c, float d) {
  union { fp16x2 h2[2]; f16x4 h4; } u;
  u.h2[0] = __builtin_amdgcn_cvt_pkrtz(a, b);
  u.h2[1] = __builtin_amdgcn_cvt_pkrtz(c, d);
  return u.h4;
}

// ---------- ka: bf16 xb + f16 transposed xth + m ----------
__global__ __launch_bounds__(256) void ka_init(const float* __restrict__ x,
                                               unsigned short* __restrict__ xb,
                                               unsigned short* __restrict__ xth,
                                               float* __restrict__ m) {
  __shared__ __align__(16) unsigned short tile[64 * 72];
  int t = threadIdx.x;
  int r0 = blockIdx.x * 64;
  int rloc = t >> 2, part = t & 3;
  int r = r0 + rloc;
  const float4* px = (const float4*)(x + (size_t)r * DD + part * 16);
  unsigned short h[16], hf[16];
  float msum = 0.f;
#pragma unroll
  for (int g = 0; g < 4; ++g) {
    float4 v = px[g];
    float vv[4] = {v.x, v.y, v.z, v.w};
#pragma unroll
    for (int e = 0; e < 4; ++e) {
      unsigned short hb = f2bf(vv[e]);
      h[g * 4 + e] = hb;
      float f = bf2f(hb);
      msum += f * f;
      _Float16 hh = (_Float16)vv[e];
      hf[g * 4 + e] = *(unsigned short*)&hh;
    }
  }
  uint4* xbr = (uint4*)(xb + (size_t)r * DD + part * 16);
#pragma unroll
  for (int g = 0; g < 2; ++g) {
    uint4 v;
    v.x = (unsigned int)h[g * 8 + 0] | ((unsigned int)h[g * 8 + 1] << 16);
    v.y = (unsigned int)h[g * 8 + 2] | ((unsigned int)h[g * 8 + 3] << 16);
    v.z = (unsigned int)h[g * 8 + 4] | ((unsigned int)h[g * 8 + 5] << 16);
    v.w = (unsigned int)h[g * 8 + 6] | ((unsigned int)h[g * 8 + 7] << 16);
    xbr[g] = v;
  }
#pragma unroll
  for (int k = 0; k < 16; ++k) tile[(part * 16 + k) * 72 + rloc] = hf[k];
  msum += __shfl_xor(msum, 1, 64);
  msum += __shfl_xor(msum, 2, 64);
  if (part == 0) m[r] = msum;
  __syncthreads();
  int d = t >> 2, seg = t & 3;
  int b = r0 >> 13;
  int tcol = (r0 & (TT - 1)) + seg * 16;
  uint4 v0 = *(uint4*)(tile + d * 72 + seg * 16);
  uint4 v1 = *(uint4*)(tile + d * 72 + seg * 16 + 8);
  uint4* dst = (uint4*)(xth + ((size_t)b * DD + d) * TT + tcol);
  dst[0] = v0;
  dst[1] = v1;
}

// ---------- kb: mm_j = m_j + ln(sum_k exp(x_j.x_k - m_j)) ----------
// 1024 blocks x 256 thr; block = 16 j; wave w sweeps k in [w*2048,...),
// k-step 16, B reg-dbuf direct-global (compiler-managed waits). No LDS in loop.
__global__ __launch_bounds__(256, 4) void kb_l(const unsigned short* __restrict__ xq,
                                               const float* __restrict__ m,
                                               float* __restrict__ mm) {
  __shared__ float lpart[4][16];
  int w = threadIdx.x >> 6, lane = threadIdx.x & 63;
  int c = lane & 15, q = lane >> 4;
  int lid = blockIdx.x;
  int b = (lid >> 2) & 1;
  int tile = (lid & 3) | ((lid >> 3) << 2);  // 0..511
  int j0g = b * TT + tile * 16;
  const unsigned short* pa = xq + (size_t)(j0g + c) * DD + q * 8;
  bf16x8 a0 = *(const bf16x8*)pa;
  bf16x8 a1 = *(const bf16x8*)(pa + 32);
  f32x4 mv = *(const f32x4*)(m + j0g + 4 * q);
  const unsigned short* xqb = xq + (size_t)(b * TT) * DD;
  int k0 = w * 2048;
  bf16x8 B[2][2];
  auto fetchB = [&](int buf, int kk) {
    const unsigned short* p = xqb + (size_t)(kk + c) * DD + q * 8;
    B[buf][0] = *(const bf16x8*)(p);
    B[buf][1] = *(const bf16x8*)(p + 32);
  };
  fetchB(0, k0);
  float ls[4] = {0.f, 0.f, 0.f, 0.f};
#pragma unroll 4
  for (int it = 0; it < 128; ++it) {
    int cur = it & 1;
    if (it < 127) fetchB(cur ^ 1, k0 + (it + 1) * 16);
    f32x4 z = {0.f, 0.f, 0.f, 0.f};
    f32x4 acc = MFMAQK(a0, B[cur][0], z, 0, 0, 0);
    acc = MFMAQK(a1, B[cur][1], acc, 0, 0, 0);
#pragma unroll
    for (int e = 0; e < 4; ++e) ls[e] += __expf(acc[e] - mv[e]);
  }
#pragma unroll
  for (int e = 0; e < 4; ++e) {
    float v = ls[e];
    v += __shfl_xor(v, 1, 64);
    v += __shfl_xor(v, 2, 64);
    v += __shfl_xor(v, 4, 64);
    v += __shfl_xor(v, 8, 64);
    if (c == 0) lpart[w][4 * q + e] = v;
  }
  __syncthreads();
  int t = threadIdx.x;
  if (t < 16) {
    float s = lpart[0][t] + lpart[1][t] + lpart[2][t] + lpart[3][t];
    mm[j0g + t] = m[j0g + t] + __logf(s);
  }
}

// ---------- kc: out[b][d][i] = sum_j exp(x_j.x_i - mm_j) * x_j[d] ----------
// 512 blocks x 256 thr; block = 32 i; wave w sweeps j-quarter 2048, j-step 32.
// A (bf16) + V (f16) per-wave DMA LDS dbuf, explicit vmcnt(10) pipeline.
// PV via 16x16x16 f16 MFMA (QK C-layout == PV A-layout: no transform).
__global__ __launch_bounds__(256, 2) void kc_out(const unsigned short* __restrict__ xq,
                                                 const unsigned short* __restrict__ xth,
                                                 const float* __restrict__ mm,
                                                 float* __restrict__ out) {
  __shared__ __align__(16) unsigned short smem[32768];  // A 4x8KB | V 4x8KB; epi overlay
  int w = threadIdx.x >> 6, lane = threadIdx.x & 63;
  int c = lane & 15, q = lane >> 4;
  int lid = blockIdx.x;
  int b = (lid >> 2) & 1;
  int tile = (lid & 3) | ((lid >> 3) << 2);
  int i0 = tile * 32;
  bf16x8 bq0[2], bq1[2];
#pragma unroll
  for (int u = 0; u < 2; ++u) {
    const unsigned short* pr = xq + (size_t)(b * TT + i0 + u * 16 + c) * DD + q * 8;
    bq0[u] = *(const bf16x8*)pr;
    bq1[u] = *(const bf16x8*)(pr + 32);
  }
  f32x4 o[2][4];
#pragma unroll
  for (int u = 0; u < 2; ++u)
#pragma unroll
    for (int nt = 0; nt < 4; ++nt) o[u][nt] = (f32x4){0.f, 0.f, 0.f, 0.f};

  const unsigned short* xqb = xq + (size_t)(b * TT) * DD;
  const unsigned short* xtb = xth + (size_t)b * DD * TT;
  const float* mmb = mm + b * TT;
  int jq0 = w * 2048;
  unsigned short* asb = smem + w * 4096;           // 2 bufs x 2048 shorts
  unsigned short* vsb = smem + 16384 + w * 4096;   // 2 bufs x 2048 shorts

  // A staging (32 rows x 64 shorts, xor-swizzled chunks of 8 shorts)
  int srow = lane >> 3;
  int sch = (lane & 7) ^ srow;
  // V staging from xth: inst t -> j-half t>>1, d-rows (t&1)*32+(lane>>1), slot lane&1
  int vd = lane >> 1;
  int vg = (lane & 1) ^ ((lane >> 1) & 1);
  auto stage = [&](int buf, int j) {
#pragma unroll
    for (int t = 0; t < 4; ++t)
      gld_lds16(xqb + (size_t)(j + t * 8 + srow) * DD + sch * 8,
                asb + buf * 2048 + t * 512);
#pragma unroll
    for (int t = 0; t < 4; ++t)
      gld_lds16(xtb + (size_t)((t & 1) * 32 + vd) * TT + j + (t >> 1) * 16 + 8 * vg,
                vsb + buf * 2048 + t * 512);
  };
  f32x4 mv0[2], mv1[2];
  stage(0, jq0);
  mv0[0] = *(const f32x4*)(mmb + jq0 + 4 * q);
  mv1[0] = *(const f32x4*)(mmb + jq0 + 16 + 4 * q);

  int o1 = (q ^ (c & 7)) * 8, o2 = ((q | 4) ^ (c & 7)) * 8;
  // V read (shorts): row d=nt*16+c, j-half jh -> +jh*1024, chunk (q>>1)^(c&1), +4*(q&1)
  int voff = c * 16 + 8 * ((q >> 1) ^ (c & 1)) + 4 * (q & 1);

  for (int it = 0; it < 64; ++it) {
    int cur = it & 1;
    int jt = jq0 + it * 32;
    if (it < 63) {
      stage(cur ^ 1, jt + 32);
      mv0[cur ^ 1] = *(const f32x4*)(mmb + jt + 32 + 4 * q);
      mv1[cur ^ 1] = *(const f32x4*)(mmb + jt + 48 + 4 * q);
      __builtin_amdgcn_s_waitcnt(0xF7A);  // vmcnt(10): drain prev iter, keep prefetch
    } else {
      __builtin_amdgcn_s_waitcnt(0xF70);  // vmcnt(0)
    }
    __builtin_amdgcn_sched_barrier(0);
    const unsigned short* ap = asb + cur * 2048;
    const unsigned short* vp = vsb + cur * 2048;
    bf16x8 a00 = *(const bf16x8*)(ap + c * 64 + o1);
    bf16x8 a01 = *(const bf16x8*)(ap + c * 64 + o2);
    bf16x8 a10 = *(const bf16x8*)(ap + (c + 16) * 64 + o1);
    bf16x8 a11 = *(const bf16x8*)(ap + (c + 16) * 64 + o2);
    f16x4 bv0[4], bv1[4];
#pragma unroll
    for (int nt = 0; nt < 4; ++nt) {
      bv0[nt] = *(const f16x4*)(vp + nt * 256 + voff);          // j-half 0
      bv1[nt] = *(const f16x4*)(vp + 1024 + nt * 256 + voff);   // j-half 1
    }
#pragma unroll
    for (int u = 0; u < 2; ++u) {
      f32x4 z = {0.f, 0.f, 0.f, 0.f};
      f32x4 s0 = MFMAQK(a00, bq0[u], z, 0, 0, 0);
      s0 = MFMAQK(a01, bq1[u], s0, 0, 0, 0);
      f32x4 s1 = MFMAQK(a10, bq0[u], z, 0, 0, 0);
      s1 = MFMAQK(a11, bq1[u], s1, 0, 0, 0);
      f16x4 p0 = pk4f16(__expf(s0[0] - mv0[cur][0]), __expf(s0[1] - mv0[cur][1]),
                        __expf(s0[2] - mv0[cur][2]), __expf(s0[3] - mv0[cur][3]));
      f16x4 p1 = pk4f16(__expf(s1[0] - mv1[cur][0]), __expf(s1[1] - mv1[cur][1]),
                        __expf(s1[2] - mv1[cur][2]), __expf(s1[3] - mv1[cur][3]));
#pragma unroll
      for (int nt = 0; nt < 4; ++nt) {
        o[u][nt] = MFMAPV(p0, bv0[nt], o[u][nt], 0, 0, 0);
        o[u][nt] = MFMAPV(p1, bv1[nt], o[u][nt], 0, 0, 0);
      }
    }
  }
  // cross-wave O reduce: per wave 64 d-rows x pitch 34 fp32 (8704 B)
  __syncthreads();
  float* ow = (float*)smem + w * 2176;
#pragma unroll
  for (int u = 0; u < 2; ++u)
#pragma unroll
    for (int nt = 0; nt < 4; ++nt)
      *(f32x4*)(ow + (nt * 16 + c) * 34 + u * 16 + 4 * q) = o[u][nt];
  __syncthreads();
  int t = threadIdx.x, d = t >> 2, i8 = (t & 3) * 8;
  const float* sbase = (const float*)smem;
  f32x4 sA = {0.f, 0.f, 0.f, 0.f}, sB = {0.f, 0.f, 0.f, 0.f};
#pragma unroll
  for (int ww = 0; ww < 4; ++ww) {
    const float* p = sbase + ww * 2176 + d * 34 + i8;
    sA += *(const f32x4*)p;
    sB += *(const f32x4*)(p + 4);
  }
  float* ob = out + ((size_t)(b * DD + d)) * TT + i0 + i8;
  *(f32x4*)ob = sA;
  *(f32x4*)(ob + 4) = sB;
}

extern "C" void kernel_launch(void* const* d_in, const int* in_sizes, int n_in,
                              void* d_out, int out_size, void* d_ws, size_t ws_size,
                              hipStream_t stream) {
  const float* x = (const float*)d_in[0];
  float* out = (float*)d_out;
  unsigned short* xb = (unsigned short*)d_ws;
  unsigned short* xth = xb + (size_t)NROWS * DD;
  float* m = (float*)(xth + (size_t)NROWS * DD);
  float* mmv = m + NROWS;

  ka_init<<<NROWS / 64, 256, 0, stream>>>(x, xb, xth, m);
  kb_l<<<1024, 256, 0, stream>>>(xb, m, mmv);
  kc_out<<<512, 256, 0, stream>>>(xb, xth, mmv, out);
}

// Round 10
// 208.884 us; speedup vs baseline: 1.3763x; 1.2569x over previous
//
#include <hip/hip_runtime.h>
#include <hip/hip_bf16.h>

#define TT 8192
#define DD 64
#define BB 2
#define NROWS (BB * TT)  // 16384

typedef __attribute__((ext_vector_type(8))) short bf16x8;
typedef __attribute__((ext_vector_type(4))) float f32x4;
typedef _Float16 f16x4 __attribute__((ext_vector_type(4)));
typedef __fp16 fp16x2 __attribute__((ext_vector_type(2)));

#define MFMAQK __builtin_amdgcn_mfma_f32_16x16x32_bf16
#define MFMAPV __builtin_amdgcn_mfma_f32_16x16x16f16

typedef __attribute__((address_space(1))) const unsigned int gu32;
typedef __attribute__((address_space(3))) unsigned int lu32;

__device__ inline void gld_lds16(const unsigned short* g, unsigned short* l) {
  __builtin_amdgcn_global_load_lds((gu32*)g, (lu32*)l, 16, 0, 0);
}

// ws: xb bf16[16384*64] 2MB | xth f16[2*64*8192] 2MB | m[16384] | mm[16384] | l[16384] | part fp32[1048576] 4MB

__device__ inline unsigned short f2bf(float f) {
  unsigned int u = __float_as_uint(f);
  u += 0x7FFF + ((u >> 16) & 1);
  return (unsigned short)(u >> 16);
}
__device__ inline float bf2f(unsigned short h) {
  return __uint_as_float(((unsigned int)h) << 16);
}
__device__ inline f16x4 pk4f16(float a, float b, float c, float d) {
  union { fp16x2 h2[2]; f16x4 h4; } u;
  u.h2[0] = __builtin_amdgcn_cvt_pkrtz(a, b);
  u.h2[1] = __builtin_amdgcn_cvt_pkrtz(c, d);
  return u.h4;
}

// ---------- ka: bf16 xb + f16 transposed xth + m ----------
__global__ __launch_bounds__(256) void ka_init(const float* __restrict__ x,
                                               unsigned short* __restrict__ xb,
                                               unsigned short* __restrict__ xth,
                                               float* __restrict__ m) {
  __shared__ __align__(16) unsigned short tile[64 * 72];
  int t = threadIdx.x;
  int r0 = blockIdx.x * 64;
  int rloc = t >> 2, part = t & 3;
  int r = r0 + rloc;
  const float4* px = (const float4*)(x + (size_t)r * DD + part * 16);
  unsigned short h[16], hf[16];
  float msum = 0.f;
#pragma unroll
  for (int g = 0; g < 4; ++g) {
    float4 v = px[g];
    float vv[4] = {v.x, v.y, v.z, v.w};
#pragma unroll
    for (int e = 0; e < 4; ++e) {
      unsigned short hb = f2bf(vv[e]);
      h[g * 4 + e] = hb;
      float f = bf2f(hb);
      msum += f * f;
      _Float16 hh = (_Float16)vv[e];
      hf[g * 4 + e] = *(unsigned short*)&hh;
    }
  }
  uint4* xbr = (uint4*)(xb + (size_t)r * DD + part * 16);
#pragma unroll
  for (int g = 0; g < 2; ++g) {
    uint4 v;
    v.x = (unsigned int)h[g * 8 + 0] | ((unsigned int)h[g * 8 + 1] << 16);
    v.y = (unsigned int)h[g * 8 + 2] | ((unsigned int)h[g * 8 + 3] << 16);
    v.z = (unsigned int)h[g * 8 + 4] | ((unsigned int)h[g * 8 + 5] << 16);
    v.w = (unsigned int)h[g * 8 + 6] | ((unsigned int)h[g * 8 + 7] << 16);
    xbr[g] = v;
  }
#pragma unroll
  for (int k = 0; k < 16; ++k) tile[(part * 16 + k) * 72 + rloc] = hf[k];
  msum += __shfl_xor(msum, 1, 64);
  msum += __shfl_xor(msum, 2, 64);
  if (part == 0) m[r] = msum;
  __syncthreads();
  int d = t >> 2, seg = t & 3;
  int b = r0 >> 13;
  int tcol = (r0 & (TT - 1)) + seg * 16;
  uint4 v0 = *(uint4*)(tile + d * 72 + seg * 16);
  uint4 v1 = *(uint4*)(tile + d * 72 + seg * 16 + 8);
  uint4* dst = (uint4*)(xth + ((size_t)b * DD + d) * TT + tcol);
  dst[0] = v0;
  dst[1] = v1;
}

// ---------- kb: l_j += sum_k exp(x_j.x_k - m_j) over k-split range ----------
// grid (256 j-tiles, 4 k-splits, 2 batch) x 256 thr; block = 32 j; wave w
// sweeps 512 k in 16-k steps, private DMA LDS slab + vmcnt(2) pipeline.
__global__ __launch_bounds__(256) void kb_l(const unsigned short* __restrict__ xq,
                                            const float* __restrict__ m,
                                            float* __restrict__ l) {
  __shared__ __align__(16) unsigned short kslab[4][2][1024];  // 16 KB
  __shared__ float lpart[4][32];
  int w = threadIdx.x >> 6, lane = threadIdx.x & 63;
  int c = lane & 15, q = lane >> 4;
  int b = blockIdx.z;
  int j0g = b * TT + blockIdx.x * 32;
  bf16x8 a0[2], a1[2];
  f32x4 mv[2];
#pragma unroll
  for (int u = 0; u < 2; ++u) {
    const unsigned short* pr = xq + (size_t)(j0g + u * 16 + c) * DD + q * 8;
    a0[u] = *(const bf16x8*)pr;
    a1[u] = *(const bf16x8*)(pr + 32);
    mv[u] = *(const f32x4*)(m + j0g + u * 16 + 4 * q);
  }
  const unsigned short* xqb = xq + (size_t)(b * TT) * DD;
  int k0 = blockIdx.y * 2048 + w * 512;
  int srow = lane >> 3;
  int sch = (lane & 7) ^ srow;
  unsigned short* sb = &kslab[w][0][0];
  auto stage = [&](int buf, int kbase) {
#pragma unroll
    for (int t = 0; t < 2; ++t)
      gld_lds16(xqb + (size_t)(kbase + t * 8 + srow) * DD + sch * 8,
                sb + buf * 1024 + t * 512);
  };
  stage(0, k0);
  float ls[2][4] = {{0.f, 0.f, 0.f, 0.f}, {0.f, 0.f, 0.f, 0.f}};
  int o1 = (q ^ (c & 7)) * 8, o2 = ((q | 4) ^ (c & 7)) * 8;
  for (int it = 0; it < 32; ++it) {
    if (it < 31) {
      stage((it & 1) ^ 1, k0 + (it + 1) * 16);
      __builtin_amdgcn_s_waitcnt(0xF72);  // prev 2 DMA done, new 2 in flight
    } else {
      __builtin_amdgcn_s_waitcnt(0xF70);
    }
    __builtin_amdgcn_sched_barrier(0);
    const unsigned short* kp = sb + (it & 1) * 1024;
    bf16x8 b00 = *(const bf16x8*)(kp + c * 64 + o1);
    bf16x8 b01 = *(const bf16x8*)(kp + c * 64 + o2);
#pragma unroll
    for (int u = 0; u < 2; ++u) {
      f32x4 z = {0.f, 0.f, 0.f, 0.f};
      f32x4 acc = MFMAQK(a0[u], b00, z, 0, 0, 0);
      acc = MFMAQK(a1[u], b01, acc, 0, 0, 0);
#pragma unroll
      for (int e = 0; e < 4; ++e) ls[u][e] += __expf(acc[e] - mv[u][e]);
    }
  }
#pragma unroll
  for (int u = 0; u < 2; ++u)
#pragma unroll
    for (int e = 0; e < 4; ++e) {
      float v = ls[u][e];
      v += __shfl_xor(v, 1, 64);
      v += __shfl_xor(v, 2, 64);
      v += __shfl_xor(v, 4, 64);
      v += __shfl_xor(v, 8, 64);
      if (c == 0) lpart[w][u * 16 + 4 * q + e] = v;
    }
  __syncthreads();
  int t = threadIdx.x;
  if (t < 32) {
    float s = lpart[0][t] + lpart[1][t] + lpart[2][t] + lpart[3][t];
    atomicAdd(&l[j0g + t], s);
  }
}

__global__ __launch_bounds__(256) void kb2(const float* __restrict__ m,
                                           const float* __restrict__ l,
                                           float* __restrict__ mm) {
  int r = blockIdx.x * 256 + threadIdx.x;
  mm[r] = m[r] + __logf(l[r]);
}

// ---------- kc: out[b][d][i] = sum_j exp(x_j.x_i - mm_j) * x_j[d] ----------
// grid (256 i-tiles, 2 j-splits, 2 batch) x 256 thr; block = 32 i; wave w
// sweeps 1024 j in 16-j steps; A(bf16)+V(f16) private DMA slabs, vmcnt(5);
// PV via 16x16x16 f16 (QK C-layout == PV A-layout); split0->out, split1->part.
__global__ __launch_bounds__(256) void kc_out(const unsigned short* __restrict__ xq,
                                              const unsigned short* __restrict__ xth,
                                              const float* __restrict__ mm,
                                              float* __restrict__ out,
                                              float* __restrict__ part) {
  __shared__ __align__(16) unsigned short smem[16384];  // A 8KB | V 8KB; epi overlay 32KB
  int w = threadIdx.x >> 6, lane = threadIdx.x & 63;
  int c = lane & 15, q = lane >> 4;
  int b = blockIdx.z;
  int i0 = blockIdx.x * 32;
  bf16x8 bq0[2], bq1[2];
#pragma unroll
  for (int u = 0; u < 2; ++u) {
    const unsigned short* pr = xq + (size_t)(b * TT + i0 + u * 16 + c) * DD + q * 8;
    bq0[u] = *(const bf16x8*)pr;
    bq1[u] = *(const bf16x8*)(pr + 32);
  }
  f32x4 o[2][4];
#pragma unroll
  for (int u = 0; u < 2; ++u)
#pragma unroll
    for (int nt = 0; nt < 4; ++nt) o[u][nt] = (f32x4){0.f, 0.f, 0.f, 0.f};

  const unsigned short* xqb = xq + (size_t)(b * TT) * DD;
  const unsigned short* xtb = xth + (size_t)b * DD * TT;
  const float* mmb = mm + b * TT;
  int jq0 = blockIdx.y * 4096 + w * 1024;
  unsigned short* asb = smem + w * 2048;          // 2 bufs x 1024 shorts
  unsigned short* vsb = smem + 8192 + w * 2048;   // 2 bufs x 1024 shorts

  int srow = lane >> 3;
  int sch = (lane & 7) ^ srow;
  int vd = lane >> 1;
  int vg = (lane & 1) ^ (vd & 1);
  auto stage = [&](int buf, int j) {
#pragma unroll
    for (int t = 0; t < 2; ++t)
      gld_lds16(xqb + (size_t)(j + t * 8 + srow) * DD + sch * 8,
                asb + buf * 1024 + t * 512);
#pragma unroll
    for (int t = 0; t < 2; ++t)
      gld_lds16(xtb + (size_t)(t * 32 + vd) * TT + j + 8 * vg,
                vsb + buf * 1024 + t * 512);
  };
  f32x4 mv[2];
  stage(0, jq0);
  mv[0] = *(const f32x4*)(mmb + jq0 + 4 * q);

  int o1 = (q ^ (c & 7)) * 8, o2 = ((q | 4) ^ (c & 7)) * 8;
  int voff = c * 16 + 8 * ((q >> 1) ^ (c & 1)) + 4 * (q & 1);

  for (int it = 0; it < 64; ++it) {
    int cur = it & 1;
    int jt = jq0 + it * 16;
    if (it < 63) {
      stage(cur ^ 1, jt + 16);
      mv[cur ^ 1] = *(const f32x4*)(mmb + jt + 16 + 4 * q);
      __builtin_amdgcn_s_waitcnt(0xF75);  // prev 5 loads done, new 5 in flight
    } else {
      __builtin_amdgcn_s_waitcnt(0xF70);
    }
    __builtin_amdgcn_sched_barrier(0);
    const unsigned short* ap = asb + cur * 1024;
    const unsigned short* vp = vsb + cur * 1024;
    bf16x8 a0f = *(const bf16x8*)(ap + c * 64 + o1);
    bf16x8 a1f = *(const bf16x8*)(ap + c * 64 + o2);
    f16x4 bv[4];
#pragma unroll
    for (int nt = 0; nt < 4; ++nt) bv[nt] = *(const f16x4*)(vp + nt * 256 + voff);
#pragma unroll
    for (int u = 0; u < 2; ++u) {
      f32x4 z = {0.f, 0.f, 0.f, 0.f};
      f32x4 s = MFMAQK(a0f, bq0[u], z, 0, 0, 0);
      s = MFMAQK(a1f, bq1[u], s, 0, 0, 0);
      f16x4 p = pk4f16(__expf(s[0] - mv[cur][0]), __expf(s[1] - mv[cur][1]),
                       __expf(s[2] - mv[cur][2]), __expf(s[3] - mv[cur][3]));
#pragma unroll
      for (int nt = 0; nt < 4; ++nt) o[u][nt] = MFMAPV(p, bv[nt], o[u][nt], 0, 0, 0);
    }
  }
  // cross-wave O reduce: per wave 64 d-rows x pitch 32 fp32 (8 KB), overlay
  __syncthreads();
  float* ow = (float*)smem + w * 2048;
#pragma unroll
  for (int u = 0; u < 2; ++u)
#pragma unroll
    for (int nt = 0; nt < 4; ++nt)
      *(f32x4*)(ow + (nt * 16 + c) * 32 + u * 16 + 4 * q) = o[u][nt];
  __syncthreads();
  int t = threadIdx.x, d = t >> 2, i8 = (t & 3) * 8;
  const float* sbase = (const float*)smem;
  f32x4 sA = {0.f, 0.f, 0.f, 0.f}, sB = {0.f, 0.f, 0.f, 0.f};
#pragma unroll
  for (int ww = 0; ww < 4; ++ww) {
    const float* p = sbase + ww * 2048 + d * 32 + i8;
    sA += *(const f32x4*)p;
    sB += *(const f32x4*)(p + 4);
  }
  float* dst = (blockIdx.y == 0) ? out : part;
  float* ob = dst + ((size_t)(b * DD + d)) * TT + i0 + i8;
  *(f32x4*)ob = sA;
  *(f32x4*)(ob + 4) = sB;
}

// ---------- kd: out += part ----------
__global__ __launch_bounds__(256) void kd_add(float* __restrict__ out,
                                              const float* __restrict__ part) {
  int t = blockIdx.x * 256 + threadIdx.x;
  f32x4* o4 = (f32x4*)out;
  const f32x4* p4 = (const f32x4*)part;
  o4[t] += p4[t];
}

extern "C" void kernel_launch(void* const* d_in, const int* in_sizes, int n_in,
                              void* d_out, int out_size, void* d_ws, size_t ws_size,
                              hipStream_t stream) {
  const float* x = (const float*)d_in[0];
  float* out = (float*)d_out;
  unsigned short* xb = (unsigned short*)d_ws;
  unsigned short* xth = xb + (size_t)NROWS * DD;
  float* m = (float*)(xth + (size_t)NROWS * DD);
  float* mmv = m + NROWS;
  float* l = mmv + NROWS;
  float* part = l + NROWS;

  hipMemsetAsync(l, 0, NROWS * sizeof(float), stream);
  ka_init<<<NROWS / 64, 256, 0, stream>>>(x, xb, xth, m);
  kb_l<<<dim3(TT / 32, 4, BB), 256, 0, stream>>>(xb, m, l);
  kb2<<<NROWS / 256, 256, 0, stream>>>(m, l, mmv);
  kc_out<<<dim3(TT / 32, 2, BB), 256, 0, stream>>>(xb, xth, mmv, out, part);
  kd_add<<<(BB * DD * TT / 4) / 256, 256, 0, stream>>>(out, part);
}